// Round 8
// baseline (143.135 us; speedup 1.0000x reference)
//
#include <hip/hip_runtime.h>
#include <stdint.h>

// MPS chain contraction, B=32768, L=256, D=16.
// R8 = R7 (core pairing, permutation-absorbed B layout, LDS-DMA frags)
//      + raw s_barrier with hand-counted s_waitcnt vmcnt(2) (never 0)
//      + phi coefficients via per-lane dwordx4 register loads, distance 2.
// Per chunk (2 pair-steps): issue 4 frag DMAs (c+1), 2 phi loads (c+2),
// compute, vmcnt(2) [drains DMAs, leaves phi in flight], s_barrier.
// Math identical to R7 (absmax 2.65e-23): pair product G_pq = C_t,p C_t+1,q
// RNE hi/lo split; A x B + A x Bswap = (Gh+Gl)(vh+vl) exactly.

typedef short  bf16x8 __attribute__((ext_vector_type(8)));
typedef float  f32x4  __attribute__((ext_vector_type(4)));
typedef int    i32x4  __attribute__((ext_vector_type(4)));
typedef unsigned int u32;

#define NPF 64
#define NPB 63
#define NP_ALLOC 66            // padded pairs per dir (uniform last-chunk DMA)
#define BWD_OFF (NP_ALLOC*4*64)
#define NCHUNK 32

#define PACK_HI(hi, lo) ((int)__builtin_amdgcn_perm((u32)(hi), (u32)(lo), 0x07060302u))

__device__ __forceinline__ u32 rne_bump(u32 u){ return u + 0x7FFFu + ((u >> 16) & 1u); }

__device__ __forceinline__ void async16(const void* g, void* l){
  __builtin_amdgcn_global_load_lds(
    (const __attribute__((address_space(1))) u32*)(uintptr_t)g,
    (__attribute__((address_space(3))) u32*)(uintptr_t)l, 16, 0, 0);
}

// Pair-fragment table; lane (m=lane&15, g=lane>>4) packs G cols 4g..4g+3,
// hi (dw0,1) and lo (dw2,3). K mapping absorbed (k=8g+j -> col 4g+(j&3)).
// fwd j: G[m][cq] = sum_r Ca[cq][p][r]*Cb[r][q][m], Ca=cm[2j], Cb=cm[2j+1]
// bwd j: G[m][cq] = sum_r Ca[m][p][r]*Cb[r][q][cq], Ca=cm[252-2j], Cb=cm[253-2j]
__global__ void build_pair_frags(const float* __restrict__ cm, i32x4* __restrict__ ws)
{
  __shared__ float Ca[512], Cb[512];
  const int bid = blockIdx.x;            // 0..65 fwd, 66..131 bwd
  const bool fwd = bid < NP_ALLOC;
  const int j  = fwd ? bid : bid - NP_ALLOC;
  const int ta = fwd ? 2*j     : 252 - 2*j;
  const int tb = fwd ? 2*j + 1 : 253 - 2*j;
  {
    const float* A = cm + ta*512;
    const float* B = cm + tb*512;
    for (int i = threadIdx.x; i < 512; i += 256){ Ca[i] = A[i]; Cb[i] = B[i]; }
  }
  __syncthreads();
  const int f    = threadIdx.x >> 6;     // combo p*2+q
  const int lane = threadIdx.x & 63;
  const int m    = lane & 15;
  const int g    = lane >> 4;
  const int p    = f >> 1, q = f & 1;
  u32 hi[4], lo[4];
  #pragma unroll
  for (int x = 0; x < 4; ++x){
    const int cq = 4*g + x;
    float acc = 0.f;
    #pragma unroll
    for (int r = 0; r < 16; ++r){
      const float a = fwd ? Ca[cq*32 + p*16 + r] : Ca[m*32 + p*16 + r];
      const float b = fwd ? Cb[r*32 + q*16 + m]  : Cb[r*32 + q*16 + cq];
      acc = fmaf(a, b, acc);
    }
    const u32 u  = __float_as_uint(acc);
    const u32 aa = rne_bump(u);
    const float hf = __uint_as_float(aa & 0xFFFF0000u);
    const u32 bb = rne_bump(__float_as_uint(acc - hf));
    hi[x] = aa >> 16; lo[x] = bb >> 16;
  }
  i32x4 w;
  w[0] = (int)(hi[0] | (hi[1] << 16));
  w[1] = (int)(hi[2] | (hi[3] << 16));
  w[2] = (int)(lo[0] | (lo[1] << 16));
  w[3] = (int)(lo[2] | (lo[3] << 16));
  ws[(fwd ? 0 : BWD_OFF) + (j*4 + f)*64 + lane] = w;
}

__global__ __launch_bounds__(256, 4) void mps_chain(
  const float* __restrict__ phi,
  const float* __restrict__ core_first,
  const float* __restrict__ core_last,
  const float* __restrict__ bias,
  const i32x4* __restrict__ ws,
  float* __restrict__ out)
{
  const int lane = threadIdx.x & 63;
  const int wv   = threadIdx.x >> 6;
  const int b0   = blockIdx.x * 32;
  const int n    = lane & 15;            // sample column
  const int g    = lane >> 4;            // holds rows 4g..4g+3
  const int half = wv & 1;
  const int s_in = half*16 + n;
  const bool isFwd = (wv < 2);
  const int dirIdx = isFwd ? 0 : 1;

  __shared__ i32x4 frag[2][2][2][4][64]; // [dir][buf][pair][combo][lane] 32KB

  const float* phiRow = phi + (size_t)(b0 + s_in) * 512;
  const i32x4* wsD = isFwd ? ws : (ws + BWD_OFF);

  // DMA: this wave stages pair-slot `half`; global src advances 512/chunk
  const i32x4* dmaSrc = wsD + half*256 + lane;       // pr = 2c + half
  i32x4* const dst0 = &frag[dirIdx][0][half][0][0];
  i32x4* const dst1 = &frag[dirIdx][1][half][0][0];

  float v[4];
  i32x4 bfr;
  const f32x4 z = {0.f,0.f,0.f,0.f};

  auto make_bfrag = [&](){
    const u32 u0 = __float_as_uint(v[0]), u1 = __float_as_uint(v[1]);
    const u32 u2 = __float_as_uint(v[2]), u3 = __float_as_uint(v[3]);
    const float l0 = v[0] - __uint_as_float(u0 & 0xFFFF0000u);
    const float l1 = v[1] - __uint_as_float(u1 & 0xFFFF0000u);
    const float l2 = v[2] - __uint_as_float(u2 & 0xFFFF0000u);
    const float l3 = v[3] - __uint_as_float(u3 & 0xFFFF0000u);
    bfr[0] = PACK_HI(u1, u0);
    bfr[1] = PACK_HI(u3, u2);
    bfr[2] = PACK_HI(__float_as_uint(l1), __float_as_uint(l0));
    bfr[3] = PACK_HI(__float_as_uint(l3), __float_as_uint(l2));
  };

  auto pair_step = [&](const i32x4* fr, float2 cA, float2 cB){
    const i32x4 G0 = fr[0], G1 = fr[64], G2 = fr[128], G3 = fr[192];
    const float c00 = cA.x*cB.x, c01 = cA.x*cB.y;
    const float c10 = cA.y*cB.x, c11 = cA.y*cB.y;
    i32x4 sw; sw[0]=bfr[2]; sw[1]=bfr[3]; sw[2]=bfr[0]; sw[3]=bfr[1];
    const bf16x8 bh = __builtin_bit_cast(bf16x8, bfr);
    const bf16x8 bs = __builtin_bit_cast(bf16x8, sw);
    f32x4 a00 = __builtin_amdgcn_mfma_f32_16x16x32_bf16(__builtin_bit_cast(bf16x8,G0), bh, z, 0,0,0);
    a00 = __builtin_amdgcn_mfma_f32_16x16x32_bf16(__builtin_bit_cast(bf16x8,G0), bs, a00, 0,0,0);
    f32x4 a01 = __builtin_amdgcn_mfma_f32_16x16x32_bf16(__builtin_bit_cast(bf16x8,G1), bh, z, 0,0,0);
    a01 = __builtin_amdgcn_mfma_f32_16x16x32_bf16(__builtin_bit_cast(bf16x8,G1), bs, a01, 0,0,0);
    f32x4 a10 = __builtin_amdgcn_mfma_f32_16x16x32_bf16(__builtin_bit_cast(bf16x8,G2), bh, z, 0,0,0);
    a10 = __builtin_amdgcn_mfma_f32_16x16x32_bf16(__builtin_bit_cast(bf16x8,G2), bs, a10, 0,0,0);
    f32x4 a11 = __builtin_amdgcn_mfma_f32_16x16x32_bf16(__builtin_bit_cast(bf16x8,G3), bh, z, 0,0,0);
    a11 = __builtin_amdgcn_mfma_f32_16x16x32_bf16(__builtin_bit_cast(bf16x8,G3), bs, a11, 0,0,0);
    #pragma unroll
    for (int i2 = 0; i2 < 4; ++i2){
      float t = c00*a00[i2];
      t = fmaf(c01, a01[i2], t);
      t = fmaf(c10, a10[i2], t);
      t = fmaf(c11, a11[i2], t);
      v[i2] = t;
    }
    make_bfrag();
  };

  // ---- init state + phi prologue ----
  const int initOff = isFwd ? 0 : 508;
  const float4 L0 = *(const float4*)(phiRow + initOff);   // fwd: idx0,1 / bwd: idx254,255
  if (isFwd){
    #pragma unroll
    for (int reg = 0; reg < 4; ++reg){
      const int r = g*4 + reg;
      v[reg] = L0.x * core_first[r] + L0.y * core_first[16 + r];
    }
  } else {
    #pragma unroll
    for (int reg = 0; reg < 4; ++reg){
      const int r = g*4 + reg;
      v[reg] = L0.z * core_last[2*r] + L0.w * core_last[2*r + 1];
    }
  }
  make_bfrag();
  float2 carry = isFwd ? make_float2(L0.z, L0.w) : make_float2(L0.x, L0.y);

  // phi chunk-coeff windows: fwd A@4+8c B@8+8c ; bwd A@504-8c B@500-8c
  const int offA = isFwd ? 4 : 504;
  const int offB = isFwd ? 8 : 500;
  const int dph  = isFwd ? 8 : -8;

  // prologue: DMA chunk 0, phi for chunks 0 and 1
  {
    #pragma unroll
    for (int f = 0; f < 4; ++f) async16(dmaSrc + f*64, dst0 + f*64);
  }
  float4 A_cur = *(const float4*)(phiRow + offA);
  float4 B_cur = *(const float4*)(phiRow + offB);
  float4 A_nxt = *(const float4*)(phiRow + offA + dph);
  float4 B_nxt = *(const float4*)(phiRow + offB + dph);
  __builtin_amdgcn_s_waitcnt(0x3F74);   // vmcnt(4): DMA done, phi may fly
  __builtin_amdgcn_s_barrier();

  const i32x4* dmaS = dmaSrc + 512;     // next issue: pr = 2+half (chunk 1)

  #pragma unroll 1
  for (int c = 0; c < NCHUNK; ++c){
    // 1) frag DMA for chunk c+1 (padded table: always in-bounds)
    i32x4* dst = (c & 1) ? dst0 : dst1;
    #pragma unroll
    for (int f = 0; f < 4; ++f) async16(dmaS + f*64, dst + f*64);
    dmaS += 512;

    // 2) phi loads for chunk c+2 (registers, 2-chunk flight)
    const float4 A_in = *(const float4*)(phiRow + offA + (c+2)*dph);
    const float4 B_in = *(const float4*)(phiRow + offB + (c+2)*dph);

    // 3) compute chunk c
    float2 cA0, cB0, cA1, cB1;
    if (isFwd){
      cA0 = carry;                        cB0 = make_float2(A_cur.x, A_cur.y);
      cA1 = make_float2(A_cur.z, A_cur.w); cB1 = make_float2(B_cur.x, B_cur.y);
      carry = make_float2(B_cur.z, B_cur.w);
    } else {
      cA0 = make_float2(A_cur.z, A_cur.w); cB0 = carry;
      cA1 = make_float2(B_cur.z, B_cur.w); cB1 = make_float2(A_cur.x, A_cur.y);
      carry = make_float2(B_cur.x, B_cur.y);
    }
    const i32x4* rd = &frag[dirIdx][c & 1][0][0][lane];
    pair_step(rd, cA0, cB0);
    if (isFwd || (2*c + 1) < NPB)
      pair_step(rd + 256, cA1, cB1);

    A_cur = A_nxt; B_cur = B_nxt; A_nxt = A_in; B_nxt = B_in;

    // 4) vmcnt(2): drain frag DMA (+ due phi), keep newest phi in flight
    __builtin_amdgcn_s_waitcnt(0x3F72);
    __builtin_amdgcn_s_barrier();
  }

  // ---- epilogue: full sync, reuse frag LDS as reduction buffer ----
  __syncthreads();
  float* red = (float*)&frag[0][0][0][0][0];     // 64 rows x 20 floats
  *(float4*)&red[(dirIdx*32 + s_in)*20 + 4*g] =
      make_float4(v[0], v[1], v[2], v[3]);
  __syncthreads();
  if (threadIdx.x < 32){
    const int s = threadIdx.x;
    float acc = bias[0];
    #pragma unroll
    for (int qq = 0; qq < 16; ++qq)
      acc += red[s*20 + qq] * red[(32 + s)*20 + qq];
    out[b0 + s] = acc;
  }
}

extern "C" void kernel_launch(void* const* d_in, const int* in_sizes, int n_in,
                              void* d_out, int out_size, void* d_ws, size_t ws_size,
                              hipStream_t stream)
{
  const float* phi  = (const float*)d_in[0];  // [32768,256,2]
  const float* cf   = (const float*)d_in[1];  // [2,16]
  const float* cm   = (const float*)d_in[2];  // [254,16,2,16]
  const float* cl   = (const float*)d_in[3];  // [16,2]
  const float* bias = (const float*)d_in[4];  // scalar
  i32x4* ws = (i32x4*)d_ws;                   // 2*66*4*64*16B = 540 KB

  build_pair_frags<<<2*NP_ALLOC, 256, 0, stream>>>(cm, ws);
  mps_chain<<<1024, 256, 0, stream>>>(phi, cf, cl, bias, ws, (float*)d_out);
}